// Round 2
// baseline (156.559 us; speedup 1.0000x reference)
//
#include <hip/hip_runtime.h>

#define NB 4          // batches per block
#define LN_EPS 1e-3f

static __device__ __forceinline__ float sgnf(float x) {
    return (x > 0.f) ? 1.f : ((x < 0.f) ? -1.f : 0.f);
}
static __device__ __forceinline__ float siluf(float x) {
    return x / (1.f + __expf(-x));
}

// ws layout (floats): [0, 2176)  h_pad[2][1088]   (zero-padded filter)
//                     [2176, 4224) sp[2][1024]    (processed symbols)

// ---------------- prep: build h_pad and sp (one block) ----------------
__global__ __launch_bounds__(256) void hd_prep(
    const float* __restrict__ h, const float* __restrict__ symbols,
    const float* __restrict__ gamma, const float* __restrict__ beta,
    float* __restrict__ ws)
{
    __shared__ float h_pad[2][1088];
    __shared__ float x_s[2][64];
    __shared__ float red[4][2];
    const int t = threadIdx.x;

    for (int idx = t; idx < 2 * 1088; idx += 256) {
        const int c = idx / 1088, j = idx - c * 1088;
        float v = 0.f;
        if (j >= 63 && j <= 1023) v = h[c * 961 + (j - 63)];
        h_pad[c][j] = v;
        ws[idx] = v;
    }
    if (t < 128) x_s[t >> 6][t & 63] = symbols[t];
    __syncthreads();

    const int c = t >> 7, tt = t & 127;
    const int lane = t & 63, wid = t >> 6;
    const int jbase = 1023 - tt;   // h_pad index = 1023 - o + i,  o = tt + 128k

    float acc[8];
    #pragma unroll
    for (int k = 0; k < 8; ++k) acc[k] = 0.f;

    #pragma unroll 8
    for (int i = 0; i < 64; ++i) {
        const float xv = x_s[c][i];
        #pragma unroll
        for (int k = 0; k < 8; ++k)
            acc[k] = fmaf(xv, h_pad[c][jbase + i - 128 * k], acc[k]);
    }

    float ps = 0.f, pq = 0.f;
    #pragma unroll
    for (int k = 0; k < 8; ++k) { ps += acc[k]; pq += acc[k] * acc[k]; }
    #pragma unroll
    for (int off = 32; off; off >>= 1) {
        ps += __shfl_xor(ps, off);
        pq += __shfl_xor(pq, off);
    }
    if (lane == 0) { red[wid][0] = ps; red[wid][1] = pq; }
    __syncthreads();

    const float sum = red[2 * c][0] + red[2 * c + 1][0];
    const float sq  = red[2 * c][1] + red[2 * c + 1][1];
    const float mu  = sum * (1.f / 1024.f);
    float var = sq * (1.f / 1024.f) - mu * mu;
    var = fmaxf(var, 0.f);
    const float rs = rsqrtf(var + LN_EPS);

    #pragma unroll
    for (int k = 0; k < 8; ++k) {
        const int d = tt + 128 * k;
        const float ln = (acc[k] - mu) * rs * gamma[d] + beta[d];
        ws[2176 + c * 1024 + d] = siluf(ln);
    }
}

// ---------------- main fused kernel ----------------
// Thread t owns outputs d = 4t..4t+3 for BOTH channels, NB batches.
// h windows from LDS via ds_read_b128; x via wave-uniform (scalar) loads.
__global__ __launch_bounds__(256) void hd_main(
    const float* __restrict__ values,
    const float* __restrict__ gamma, const float* __restrict__ beta,
    const float* __restrict__ ws, float* __restrict__ out)
{
    __shared__ float h_pad[2][1088];
    __shared__ float red[4][16];
    __shared__ float redf[16];
    __shared__ float red2[4][16];
    __shared__ float redf2[16];

    const int t = threadIdx.x;
    const int lane = t & 63, wid = t >> 6;
    const size_t b0 = (size_t)blockIdx.x * NB;

    for (int idx = t; idx < 2 * 1088; idx += 256)
        (&h_pad[0][0])[idx] = ws[idx];
    __syncthreads();

    const int wbase = 1020 - 4 * t;   // window start in h_pad[c]; used idx <= wbase+67 <= 1087

    float acc[NB][2][4];
    #pragma unroll
    for (int b = 0; b < NB; ++b)
        #pragma unroll
        for (int c = 0; c < 2; ++c)
            #pragma unroll
            for (int k = 0; k < 4; ++k) acc[b][c][k] = 0.f;

    // ---- grouped conv: y[d] = sum_i x[i] * h_pad[1023 - d + i]
    // window w[c][j] = h_pad[c][wbase + i0 + j]; tap (i0+il, k) uses j = il + 3 - k in [0,10]
    #pragma unroll 2
    for (int i0 = 0; i0 < 64; i0 += 8) {
        float w[2][12];
        #pragma unroll
        for (int c = 0; c < 2; ++c) {
            const float4* p = reinterpret_cast<const float4*>(&h_pad[c][wbase + i0]);
            const float4 q0 = p[0], q1 = p[1], q2 = p[2];
            w[c][0] = q0.x; w[c][1] = q0.y; w[c][2]  = q0.z; w[c][3]  = q0.w;
            w[c][4] = q1.x; w[c][5] = q1.y; w[c][6]  = q1.z; w[c][7]  = q1.w;
            w[c][8] = q2.x; w[c][9] = q2.y; w[c][10] = q2.z; w[c][11] = q2.w;
        }
        #pragma unroll
        for (int b = 0; b < NB; ++b) {
            #pragma unroll
            for (int c = 0; c < 2; ++c) {
                const float* xp = values + ((b0 + b) * 2 + c) * 64 + i0;  // wave-uniform addr
                #pragma unroll
                for (int il = 0; il < 8; ++il) {
                    const float xv = xp[il];
                    #pragma unroll
                    for (int k = 0; k < 4; ++k)
                        acc[b][c][k] = fmaf(xv, w[c][il + 3 - k], acc[b][c][k]);
                }
            }
        }
    }

    // ---- LayerNorm reductions: 16 partials (b,c)x(sum,sq) over the block's 1024 d
    {
        float v16[16];
        #pragma unroll
        for (int b = 0; b < NB; ++b)
            #pragma unroll
            for (int c = 0; c < 2; ++c) {
                const float a0 = acc[b][c][0], a1 = acc[b][c][1];
                const float a2 = acc[b][c][2], a3 = acc[b][c][3];
                v16[(b * 2 + c) * 2]     = a0 + a1 + a2 + a3;
                v16[(b * 2 + c) * 2 + 1] = a0 * a0 + a1 * a1 + a2 * a2 + a3 * a3;
            }
        #pragma unroll
        for (int off = 32; off; off >>= 1)
            #pragma unroll
            for (int v = 0; v < 16; ++v)
                v16[v] += __shfl_xor(v16[v], off);
        if (lane == 0) {
            #pragma unroll
            for (int v = 0; v < 16; ++v) red[wid][v] = v16[v];
        }
    }
    __syncthreads();
    if (t < 16) redf[t] = red[0][t] + red[1][t] + red[2][t] + red[3][t];
    __syncthreads();

    // per-thread parameters for its 4 d's
    const float4 g4  = *reinterpret_cast<const float4*>(&gamma[4 * t]);
    const float4 be4 = *reinterpret_cast<const float4*>(&beta[4 * t]);
    float sp_r[2][4];
    #pragma unroll
    for (int a = 0; a < 2; ++a) {
        const float4 s4 = *reinterpret_cast<const float4*>(&ws[2176 + a * 1024 + 4 * t]);
        sp_r[a][0] = s4.x; sp_r[a][1] = s4.y; sp_r[a][2] = s4.z; sp_r[a][3] = s4.w;
    }
    const float gk[4] = {g4.x, g4.y, g4.z, g4.w};
    const float bk[4] = {be4.x, be4.y, be4.z, be4.w};

    // ---- LN + SiLU in registers: acc becomes vp
    #pragma unroll
    for (int b = 0; b < NB; ++b)
        #pragma unroll
        for (int c = 0; c < 2; ++c) {
            const float sum = redf[(b * 2 + c) * 2];
            const float sq  = redf[(b * 2 + c) * 2 + 1];
            const float mu  = sum * (1.f / 1024.f);
            float var = sq * (1.f / 1024.f) - mu * mu;
            var = fmaxf(var, 0.f);
            const float rs = rsqrtf(var + LN_EPS);
            #pragma unroll
            for (int k = 0; k < 4; ++k)
                acc[b][c][k] = siluf((acc[b][c][k] - mu) * rs * gk[k] + bk[k]);
        }

    // ---- S[b][a][c] partials over this thread's 4 d's
    {
        float v16[16];
        #pragma unroll
        for (int b = 0; b < NB; ++b)
            #pragma unroll
            for (int a = 0; a < 2; ++a)
                #pragma unroll
                for (int c = 0; c < 2; ++c) {
                    float s = 0.f;
                    #pragma unroll
                    for (int k = 0; k < 4; ++k)
                        s += sgnf(acc[b][c][k]) * sgnf(acc[b][c][k] + sp_r[a][k]);
                    v16[b * 4 + a * 2 + c] = s;
                }
        #pragma unroll
        for (int off = 32; off; off >>= 1)
            #pragma unroll
            for (int v = 0; v < 16; ++v)
                v16[v] += __shfl_xor(v16[v], off);
        if (lane == 0) {
            #pragma unroll
            for (int v = 0; v < 16; ++v) red2[wid][v] = v16[v];
        }
    }
    __syncthreads();
    if (t < 16) redf2[t] = red2[0][t] + red2[1][t] + red2[2][t] + red2[3][t];
    __syncthreads();

    // ---- softmax over c (2-wide) + attn + silu + store
    #pragma unroll
    for (int b = 0; b < NB; ++b) {
        #pragma unroll
        for (int a = 0; a < 2; ++a) {
            const float s0 = redf2[b * 4 + a * 2 + 0] * (1.f / 1024.f);
            const float s1 = redf2[b * 4 + a * 2 + 1] * (1.f / 1024.f);
            const float m  = fmaxf(s0, s1);
            const float e0 = __expf(s0 - m), e1 = __expf(s1 - m);
            const float inv = 1.f / (e0 + e1);
            const float p0 = e0 * inv, p1 = e1 * inv;
            float4 o;
            o.x = siluf((p0 * acc[b][0][0] + p1 * acc[b][1][0]) * sp_r[a][0]);
            o.y = siluf((p0 * acc[b][0][1] + p1 * acc[b][1][1]) * sp_r[a][1]);
            o.z = siluf((p0 * acc[b][0][2] + p1 * acc[b][1][2]) * sp_r[a][2]);
            o.w = siluf((p0 * acc[b][0][3] + p1 * acc[b][1][3]) * sp_r[a][3]);
            *reinterpret_cast<float4*>(out + ((b0 + b) * 2 + a) * 1024 + 4 * t) = o;
        }
    }
}

extern "C" void kernel_launch(void* const* d_in, const int* in_sizes, int n_in,
                              void* d_out, int out_size, void* d_ws, size_t ws_size,
                              hipStream_t stream) {
    const float* values  = (const float*)d_in[0];
    const float* h       = (const float*)d_in[1];
    const float* gamma   = (const float*)d_in[2];
    const float* beta    = (const float*)d_in[3];
    const float* symbols = (const float*)d_in[4];
    float* out = (float*)d_out;
    float* ws  = (float*)d_ws;

    const int B = in_sizes[0] / 128;   // 16384

    hipLaunchKernelGGL(hd_prep, dim3(1), dim3(256), 0, stream,
                       h, symbols, gamma, beta, ws);
    hipLaunchKernelGGL(hd_main, dim3(B / NB), dim3(256), 0, stream,
                       values, gamma, beta, ws, out);
}

// Round 3
// 131.321 us; speedup vs baseline: 1.1922x; 1.1922x over previous
//
#include <hip/hip_runtime.h>

#define NB 4          // batches per block
#define LN_EPS 1e-3f

static __device__ __forceinline__ float sgnf(float x) {
    return (x > 0.f) ? 1.f : ((x < 0.f) ? -1.f : 0.f);
}
static __device__ __forceinline__ float siluf(float x) {
    return x / (1.f + __expf(-x));
}

// ws layout (floats): [0, 2176)   hrev[2][1088], hrev[c][q] = h_pad[c][1086-q] (0 outside)
//                     [2176, 4224) sp[2][1024]   (processed symbols)

// ---------------- prep: build hrev and sp (one block) ----------------
__global__ __launch_bounds__(256) void hd_prep(
    const float* __restrict__ h, const float* __restrict__ symbols,
    const float* __restrict__ gamma, const float* __restrict__ beta,
    float* __restrict__ ws)
{
    __shared__ float h_pad[2][1088];
    __shared__ float x_s[2][64];
    __shared__ float red[4][2];
    const int t = threadIdx.x;

    for (int idx = t; idx < 2 * 1088; idx += 256) {
        const int c = idx / 1088, j = idx - c * 1088;
        float v = 0.f;
        if (j >= 63 && j <= 1023) v = h[c * 961 + (j - 63)];
        h_pad[c][j] = v;
        // reversed copy for hd_main: hrev[c][q] = h_pad[c][1086 - q]
        const int src = 1086 - j;   // q = j here; recompute value for index 1086-j
        float vr = 0.f;
        if (src >= 63 && src <= 1023) vr = h[c * 961 + (src - 63)];
        ws[c * 1088 + j] = vr;
    }
    if (t < 128) x_s[t >> 6][t & 63] = symbols[t];
    __syncthreads();

    const int c = t >> 7, tt = t & 127;
    const int lane = t & 63, wid = t >> 6;
    const int jbase = 1023 - tt;   // h_pad index = 1023 - o + i,  o = tt + 128k

    float acc[8];
    #pragma unroll
    for (int k = 0; k < 8; ++k) acc[k] = 0.f;

    #pragma unroll 8
    for (int i = 0; i < 64; ++i) {
        const float xv = x_s[c][i];
        #pragma unroll
        for (int k = 0; k < 8; ++k)
            acc[k] = fmaf(xv, h_pad[c][jbase + i - 128 * k], acc[k]);
    }

    float ps = 0.f, pq = 0.f;
    #pragma unroll
    for (int k = 0; k < 8; ++k) { ps += acc[k]; pq += acc[k] * acc[k]; }
    #pragma unroll
    for (int off = 32; off; off >>= 1) {
        ps += __shfl_xor(ps, off);
        pq += __shfl_xor(pq, off);
    }
    if (lane == 0) { red[wid][0] = ps; red[wid][1] = pq; }
    __syncthreads();

    const float sum = red[2 * c][0] + red[2 * c + 1][0];
    const float sq  = red[2 * c][1] + red[2 * c + 1][1];
    const float mu  = sum * (1.f / 1024.f);
    float var = sq * (1.f / 1024.f) - mu * mu;
    var = fmaxf(var, 0.f);
    const float rs = rsqrtf(var + LN_EPS);

    #pragma unroll
    for (int k = 0; k < 8; ++k) {
        const int d = tt + 128 * k;
        const float ln = (acc[k] - mu) * rs * gamma[d] + beta[d];
        ws[2176 + c * 1024 + d] = siluf(ln);
    }
}

// ---------------- main fused kernel ----------------
// Thread t owns outputs d = 4t..4t+3 for BOTH channels, NB batches.
// Filter windows from LDS (reversed layout -> ascending conflict-free b128 reads);
// x via wave-uniform (scalar) loads.
__global__ __launch_bounds__(256, 4) void hd_main(
    const float* __restrict__ values,
    const float* __restrict__ gamma, const float* __restrict__ beta,
    const float* __restrict__ ws, float* __restrict__ out)
{
    __shared__ float hrev[2][1088];
    __shared__ float red[4][16];
    __shared__ float redf[16];
    __shared__ float red2[4][16];
    __shared__ float redf2[16];

    const int t = threadIdx.x;
    const int lane = t & 63, wid = t >> 6;
    const size_t b0 = (size_t)blockIdx.x * NB;

    for (int idx = t; idx < 2 * 1088; idx += 256)
        (&hrev[0][0])[idx] = ws[idx];
    __syncthreads();

    float acc[NB][2][4];
    #pragma unroll
    for (int b = 0; b < NB; ++b)
        #pragma unroll
        for (int c = 0; c < 2; ++c)
            #pragma unroll
            for (int k = 0; k < 4; ++k) acc[b][c][k] = 0.f;

    // ---- grouped conv: y[4t+k] = sum_i x[i] * h_pad[1023-(4t+k)+i]
    // hrev[q] = h_pad[1086-q]; window r[m] = hrev[56+4t-i0+m], m=0..11 (ascending, aligned)
    // tap (i0+il, k) uses r[7-il+k]
    #pragma unroll 1
    for (int i0 = 0; i0 < 64; i0 += 8) {
        const int q0 = 56 + 4 * t - i0;
        float r[2][12];
        #pragma unroll
        for (int c = 0; c < 2; ++c) {
            const float4* p = reinterpret_cast<const float4*>(&hrev[c][q0]);
            const float4 a0 = p[0], a1 = p[1], a2 = p[2];
            r[c][0] = a0.x; r[c][1] = a0.y; r[c][2]  = a0.z; r[c][3]  = a0.w;
            r[c][4] = a1.x; r[c][5] = a1.y; r[c][6]  = a1.z; r[c][7]  = a1.w;
            r[c][8] = a2.x; r[c][9] = a2.y; r[c][10] = a2.z; r[c][11] = a2.w;
        }
        #pragma unroll
        for (int b = 0; b < NB; ++b) {
            #pragma unroll
            for (int c = 0; c < 2; ++c) {
                const float* xp = values + ((b0 + b) * 2 + c) * 64 + i0;  // wave-uniform addr
                #pragma unroll
                for (int il = 0; il < 8; ++il) {
                    const float xv = xp[il];
                    #pragma unroll
                    for (int k = 0; k < 4; ++k)
                        acc[b][c][k] = fmaf(xv, r[c][7 - il + k], acc[b][c][k]);
                }
            }
        }
    }

    // ---- LayerNorm reductions: 16 partials (b,c)x(sum,sq) over the block's 1024 d
    {
        float v16[16];
        #pragma unroll
        for (int b = 0; b < NB; ++b)
            #pragma unroll
            for (int c = 0; c < 2; ++c) {
                const float a0 = acc[b][c][0], a1 = acc[b][c][1];
                const float a2 = acc[b][c][2], a3 = acc[b][c][3];
                v16[(b * 2 + c) * 2]     = a0 + a1 + a2 + a3;
                v16[(b * 2 + c) * 2 + 1] = a0 * a0 + a1 * a1 + a2 * a2 + a3 * a3;
            }
        #pragma unroll
        for (int off = 32; off; off >>= 1)
            #pragma unroll
            for (int v = 0; v < 16; ++v)
                v16[v] += __shfl_xor(v16[v], off);
        if (lane == 0) {
            #pragma unroll
            for (int v = 0; v < 16; ++v) red[wid][v] = v16[v];
        }
    }
    __syncthreads();
    if (t < 16) redf[t] = red[0][t] + red[1][t] + red[2][t] + red[3][t];
    __syncthreads();

    // per-thread parameters for its 4 d's
    const float4 g4  = *reinterpret_cast<const float4*>(&gamma[4 * t]);
    const float4 be4 = *reinterpret_cast<const float4*>(&beta[4 * t]);
    float sp_r[2][4];
    #pragma unroll
    for (int a = 0; a < 2; ++a) {
        const float4 s4 = *reinterpret_cast<const float4*>(&ws[2176 + a * 1024 + 4 * t]);
        sp_r[a][0] = s4.x; sp_r[a][1] = s4.y; sp_r[a][2] = s4.z; sp_r[a][3] = s4.w;
    }
    const float gk[4] = {g4.x, g4.y, g4.z, g4.w};
    const float bk[4] = {be4.x, be4.y, be4.z, be4.w};

    // ---- LN + SiLU in registers: acc becomes vp
    #pragma unroll
    for (int b = 0; b < NB; ++b)
        #pragma unroll
        for (int c = 0; c < 2; ++c) {
            const float sum = redf[(b * 2 + c) * 2];
            const float sq  = redf[(b * 2 + c) * 2 + 1];
            const float mu  = sum * (1.f / 1024.f);
            float var = sq * (1.f / 1024.f) - mu * mu;
            var = fmaxf(var, 0.f);
            const float rs = rsqrtf(var + LN_EPS);
            #pragma unroll
            for (int k = 0; k < 4; ++k)
                acc[b][c][k] = siluf((acc[b][c][k] - mu) * rs * gk[k] + bk[k]);
        }

    // ---- S[b][a][c] partials over this thread's 4 d's
    {
        float v16[16];
        #pragma unroll
        for (int b = 0; b < NB; ++b)
            #pragma unroll
            for (int a = 0; a < 2; ++a)
                #pragma unroll
                for (int c = 0; c < 2; ++c) {
                    float s = 0.f;
                    #pragma unroll
                    for (int k = 0; k < 4; ++k)
                        s += sgnf(acc[b][c][k]) * sgnf(acc[b][c][k] + sp_r[a][k]);
                    v16[b * 4 + a * 2 + c] = s;
                }
        #pragma unroll
        for (int off = 32; off; off >>= 1)
            #pragma unroll
            for (int v = 0; v < 16; ++v)
                v16[v] += __shfl_xor(v16[v], off);
        if (lane == 0) {
            #pragma unroll
            for (int v = 0; v < 16; ++v) red2[wid][v] = v16[v];
        }
    }
    __syncthreads();
    if (t < 16) redf2[t] = red2[0][t] + red2[1][t] + red2[2][t] + red2[3][t];
    __syncthreads();

    // ---- softmax over c (2-wide) + attn + silu + store
    #pragma unroll
    for (int b = 0; b < NB; ++b) {
        #pragma unroll
        for (int a = 0; a < 2; ++a) {
            const float s0 = redf2[b * 4 + a * 2 + 0] * (1.f / 1024.f);
            const float s1 = redf2[b * 4 + a * 2 + 1] * (1.f / 1024.f);
            const float m  = fmaxf(s0, s1);
            const float e0 = __expf(s0 - m), e1 = __expf(s1 - m);
            const float inv = 1.f / (e0 + e1);
            const float p0 = e0 * inv, p1 = e1 * inv;
            float4 o;
            o.x = siluf((p0 * acc[b][0][0] + p1 * acc[b][1][0]) * sp_r[a][0]);
            o.y = siluf((p0 * acc[b][0][1] + p1 * acc[b][1][1]) * sp_r[a][1]);
            o.z = siluf((p0 * acc[b][0][2] + p1 * acc[b][1][2]) * sp_r[a][2]);
            o.w = siluf((p0 * acc[b][0][3] + p1 * acc[b][1][3]) * sp_r[a][3]);
            *reinterpret_cast<float4*>(out + ((b0 + b) * 2 + a) * 1024 + 4 * t) = o;
        }
    }
}

extern "C" void kernel_launch(void* const* d_in, const int* in_sizes, int n_in,
                              void* d_out, int out_size, void* d_ws, size_t ws_size,
                              hipStream_t stream) {
    const float* values  = (const float*)d_in[0];
    const float* h       = (const float*)d_in[1];
    const float* gamma   = (const float*)d_in[2];
    const float* beta    = (const float*)d_in[3];
    const float* symbols = (const float*)d_in[4];
    float* out = (float*)d_out;
    float* ws  = (float*)d_ws;

    const int B = in_sizes[0] / 128;   // 16384

    hipLaunchKernelGGL(hd_prep, dim3(1), dim3(256), 0, stream,
                       h, symbols, gamma, beta, ws);
    hipLaunchKernelGGL(hd_main, dim3(B / NB), dim3(256), 0, stream,
                       values, gamma, beta, ws, out);
}